// Round 2
// baseline (285.917 us; speedup 1.0000x reference)
//
#include <hip/hip_runtime.h>
#include <math.h>

#define BB 32
#define SS 4096
#define DD 256
#define DAA 128
#define DPP 64
#define CHUNKS 32
#define ROWS_PER_BLOCK (SS / CHUNKS)                     // 128
#define WAVES_PER_BLOCK 4
#define ROWS_PER_WAVE (ROWS_PER_BLOCK / WAVES_PER_BLOCK) // 32
#define BATCH 8
#define NBATCH (ROWS_PER_WAVE / BATCH)                   // 4
#define VH_SLICES 8
#define SLICE (DAA / VH_SLICES)                          // 16

// workspace layout (float elements)
#define WS_VHP  0                         // 8 x 256 partial vh
#define WS_VQP  (WS_VHP + VH_SLICES*DD)   // 8 x 256 partial vq
#define WS_VP   (WS_VQP + VH_SLICES*DD)   // 128: [vp1[64] | vp2[64]]
#define WS_BC   (WS_VP + 128)
#define WS_PART (WS_BC + 16)              // 16B-aligned
#define PART_STRIDE 258                   // [l, ctx[256], pad]

typedef float f4 __attribute__((ext_vector_type(4)));
typedef float f2 __attribute__((ext_vector_type(2)));

// ---------------------------------------------------------------------------
// Kernel 0: fold Wc into projection vectors. Blocks 0..7 each do a 16-row
// slice of the Wh/Wq dots; block 8 does vp1/vp2/bc. main sums the 8
// partials per lane.
// ---------------------------------------------------------------------------
__global__ void prep_kernel(const float* __restrict__ Wh,
                            const float* __restrict__ Wq,
                            const float* __restrict__ Wp1,
                            const float* __restrict__ Wp2,
                            const float* __restrict__ Wc,
                            const float* __restrict__ bc,
                            float* __restrict__ ws) {
    const int tid = threadIdx.x; // 256 threads
    const int blk = blockIdx.x;
    if (blk < VH_SLICES) {
        const int a0 = blk * SLICE;
        float vh = 0.f, vq = 0.f;
        #pragma unroll
        for (int i = 0; i < SLICE; ++i) {
            const int a = a0 + i;
            vh += Wh[a * DD + tid] * Wc[a];
            vq += Wq[a * DD + tid] * Wc[DAA + a];
        }
        ws[WS_VHP + blk * DD + tid] = vh;
        ws[WS_VQP + blk * DD + tid] = vq;
    } else {
        if (tid < DPP) {
            float vp1 = 0.f, vp2 = 0.f;
            for (int a = 0; a < DPP; ++a) {
                vp1 += Wp1[a * DPP + tid] * Wc[2 * DAA + a];
                vp2 += Wp2[a * DPP + tid] * Wc[2 * DAA + DPP + a];
            }
            ws[WS_VP + tid]       = vp1;   // lanes 0..31 read pairs from here
            ws[WS_VP + DPP + tid] = vp2;   // lanes 32..63 read pairs from here
        }
        if (tid == 0) ws[WS_BC] = bc[0];
    }
}

// ---------------------------------------------------------------------------
// Kernel 1: streaming tanh-softmax context.
// R7 restructure: CHUNKS 64->32 (128 rows/block, preamble amortized 2x),
// grid 32x32=1024 = exactly 4 resident blocks/CU at (256,4) -> one
// perfectly balanced round, no 6+2 tail. NBATCH=4 with double-buffered
// batch pipeline (issue next batch's loads while computing current) so
// HBM latency hides under compute instead of serializing per batch.
// Bulk reads stay nontemporal (R4). No __threadfence (R5).
// ---------------------------------------------------------------------------
#define LOADB(H, P, IB)                                                        \
    {                                                                          \
        const int sb_ = s0 + (IB) * BATCH;                                     \
        _Pragma("unroll")                                                      \
        for (int j = 0; j < BATCH; ++j) {                                      \
            const int s_ = sb_ + j;                                            \
            H[j] = __builtin_nontemporal_load(hbase + (size_t)s_ * (DD / 4) + lane); \
            P[j] = __builtin_nontemporal_load((const f2*)(pfsel + (size_t)s_ * DPP)); \
        }                                                                      \
    }

#define COMPUTE(H, P)                                                          \
    {                                                                          \
        float part[BATCH];                                                     \
        _Pragma("unroll")                                                      \
        for (int j = 0; j < BATCH; ++j)                                        \
            part[j] = H[j].x * vh4.x + H[j].y * vh4.y                          \
                    + H[j].z * vh4.z + H[j].w * vh4.w                          \
                    + P[j].x * vpl.x + P[j].y * vpl.y;                         \
        _Pragma("unroll")                                                      \
        for (int off = 32; off >= 1; off >>= 1) {                              \
            _Pragma("unroll")                                                  \
            for (int j = 0; j < BATCH; ++j)                                    \
                part[j] += __shfl_xor(part[j], off, 64);                       \
        }                                                                      \
        _Pragma("unroll")                                                      \
        for (int j = 0; j < BATCH; ++j) {                                      \
            const float score = part[j] + qd;                                  \
            const float e2 = __expf(2.f * score);                              \
            const float t  = 1.f - 2.f * __builtin_amdgcn_rcpf(e2 + 1.f);      \
            const float w  = __expf(t);                                        \
            l += w;                                                            \
            ctx.x += w * H[j].x;                                               \
            ctx.y += w * H[j].y;                                               \
            ctx.z += w * H[j].z;                                               \
            ctx.w += w * H[j].w;                                               \
        }                                                                      \
    }

__global__ __launch_bounds__(256, 4) void
main_kernel(const float* __restrict__ h,
            const float* __restrict__ q,
            const float* __restrict__ pf1,
            const float* __restrict__ pf2,
            float* __restrict__ ws) {
    const int c    = blockIdx.x;
    const int b    = blockIdx.y;
    const int tid  = threadIdx.x;
    const int wave = tid >> 6;
    const int lane = tid & 63;
    const int ll   = lane & 31;

    // per-lane constants: sum the 8 prep partials (L2-hot)
    f4 vh4 = {0.f, 0.f, 0.f, 0.f};
    f4 vq4 = {0.f, 0.f, 0.f, 0.f};
    #pragma unroll
    for (int k = 0; k < VH_SLICES; ++k) {
        vh4 += ((const f4*)(ws + WS_VHP + k * DD))[lane];
        vq4 += ((const f4*)(ws + WS_VQP + k * DD))[lane];
    }
    const f2 vpl = ((const f2*)(ws + WS_VP))[lane];

    // per-batch q scalar, computed redundantly per wave (cached reads)
    const float4 q4 = ((const float4*)(q + (size_t)b * DD))[lane];
    float qp = q4.x * vq4.x + q4.y * vq4.y + q4.z * vq4.z + q4.w * vq4.w;
    #pragma unroll
    for (int off = 32; off >= 1; off >>= 1) qp += __shfl_xor(qp, off, 64);
    const float qd = qp + ws[WS_BC];

    const int s0 = c * ROWS_PER_BLOCK + wave * ROWS_PER_WAVE;
    const f4*    hbase = (const f4*)(h + (size_t)b * SS * DD);
    const float* pfsel = ((lane < 32) ? pf1 : pf2) + (size_t)b * SS * DPP + 2 * ll;

    float  l = 0.f;
    float4 ctx = make_float4(0.f, 0.f, 0.f, 0.f);

    // double-buffered batch pipeline over NBATCH=4
    f4 hA[BATCH], hB[BATCH];
    f2 pA[BATCH], pB[BATCH];
    LOADB(hA, pA, 0)
    LOADB(hB, pB, 1)
    COMPUTE(hA, pA)
    LOADB(hA, pA, 2)
    COMPUTE(hB, pB)
    LOADB(hB, pB, 3)
    COMPUTE(hA, pA)
    COMPUTE(hB, pB)

    // combine the block's 4 waves in LDS, then one plain store per thread
    __shared__ float s_l[WAVES_PER_BLOCK];
    __shared__ float s_ctx[WAVES_PER_BLOCK][DD];
    if (lane == 0) s_l[wave] = l;
    ((float4*)s_ctx[wave])[lane] = ctx;
    __syncthreads();

    const float cd = s_ctx[0][tid] + s_ctx[1][tid] + s_ctx[2][tid] + s_ctx[3][tid];
    float* part_out = ws + WS_PART + (size_t)(b * CHUNKS + c) * PART_STRIDE;
    part_out[1 + tid] = cd;
    if (tid == 0) part_out[0] = s_l[0] + s_l[1] + s_l[2] + s_l[3];
}

// ---------------------------------------------------------------------------
// Kernel 2: merge the CHUNKS partials per batch, scale by 1/(L*S).
// ---------------------------------------------------------------------------
__global__ void finalize_kernel(const float* __restrict__ ws,
                                float* __restrict__ out) {
    const int b   = blockIdx.x;
    const int tid = threadIdx.x; // 256
    __shared__ float s_l[CHUNKS];
    const float* base = ws + WS_PART + (size_t)b * CHUNKS * PART_STRIDE;
    if (tid < CHUNKS) s_l[tid] = base[(size_t)tid * PART_STRIDE];
    __syncthreads();
    float L = 0.f, acc = 0.f;
    #pragma unroll 8
    for (int c = 0; c < CHUNKS; ++c) {
        L   += s_l[c];
        acc += base[(size_t)c * PART_STRIDE + 1 + tid];
    }
    out[b * DD + tid] = acc / (L * (float)SS);
}

extern "C" void kernel_launch(void* const* d_in, const int* in_sizes, int n_in,
                              void* d_out, int out_size, void* d_ws, size_t ws_size,
                              hipStream_t stream) {
    const float* h   = (const float*)d_in[0];
    const float* q   = (const float*)d_in[1];
    const float* pf1 = (const float*)d_in[2];
    const float* pf2 = (const float*)d_in[3];
    const float* Wh  = (const float*)d_in[4];
    const float* Wq  = (const float*)d_in[5];
    const float* Wp1 = (const float*)d_in[6];
    const float* Wp2 = (const float*)d_in[7];
    const float* Wc  = (const float*)d_in[8];
    const float* bc  = (const float*)d_in[9];
    float* out = (float*)d_out;
    float* ws  = (float*)d_ws;

    prep_kernel<<<VH_SLICES + 1, 256, 0, stream>>>(Wh, Wq, Wp1, Wp2, Wc, bc, ws);
    main_kernel<<<dim3(CHUNKS, BB), 256, 0, stream>>>(h, q, pf1, pf2, ws);
    finalize_kernel<<<BB, 256, 0, stream>>>(ws, out);
}

// Round 3
// 270.334 us; speedup vs baseline: 1.0576x; 1.0576x over previous
//
#include <hip/hip_runtime.h>
#include <math.h>

#define BB 32
#define SS 4096
#define DD 256
#define DAA 128
#define DPP 64
#define CHUNKS 32
#define ROWS_PER_BLOCK (SS / CHUNKS)                     // 128
#define WAVES_PER_BLOCK 4
#define ROWS_PER_WAVE (ROWS_PER_BLOCK / WAVES_PER_BLOCK) // 32
#define BATCH 4
#define NBATCH (ROWS_PER_WAVE / BATCH)                   // 8
#define VH_SLICES 8
#define SLICE (DAA / VH_SLICES)                          // 16

// workspace layout (float elements)
#define WS_VHP  0                         // 8 x 256 partial vh
#define WS_VQP  (WS_VHP + VH_SLICES*DD)   // 8 x 256 partial vq
#define WS_VP   (WS_VQP + VH_SLICES*DD)   // 128: [vp1[64] | vp2[64]]
#define WS_BC   (WS_VP + 128)
#define WS_PART (WS_BC + 16)              // 16B-aligned
#define PART_STRIDE 258                   // [l, ctx[256], pad]

typedef float f4 __attribute__((ext_vector_type(4)));
typedef float f2 __attribute__((ext_vector_type(2)));

// ---------------------------------------------------------------------------
// Kernel 0: fold Wc into projection vectors. Blocks 0..7 each do a 16-row
// slice of the Wh/Wq dots; block 8 does vp1/vp2/bc. main sums the 8
// partials per lane.
// ---------------------------------------------------------------------------
__global__ void prep_kernel(const float* __restrict__ Wh,
                            const float* __restrict__ Wq,
                            const float* __restrict__ Wp1,
                            const float* __restrict__ Wp2,
                            const float* __restrict__ Wc,
                            const float* __restrict__ bc,
                            float* __restrict__ ws) {
    const int tid = threadIdx.x; // 256 threads
    const int blk = blockIdx.x;
    if (blk < VH_SLICES) {
        const int a0 = blk * SLICE;
        float vh = 0.f, vq = 0.f;
        #pragma unroll
        for (int i = 0; i < SLICE; ++i) {
            const int a = a0 + i;
            vh += Wh[a * DD + tid] * Wc[a];
            vq += Wq[a * DD + tid] * Wc[DAA + a];
        }
        ws[WS_VHP + blk * DD + tid] = vh;
        ws[WS_VQP + blk * DD + tid] = vq;
    } else {
        if (tid < DPP) {
            float vp1 = 0.f, vp2 = 0.f;
            for (int a = 0; a < DPP; ++a) {
                vp1 += Wp1[a * DPP + tid] * Wc[2 * DAA + a];
                vp2 += Wp2[a * DPP + tid] * Wc[2 * DAA + DPP + a];
            }
            ws[WS_VP + tid]       = vp1;   // lanes 0..31 read pairs from here
            ws[WS_VP + DPP + tid] = vp2;   // lanes 32..63 read pairs from here
        }
        if (tid == 0) ws[WS_BC] = bc[0];
    }
}

// ---------------------------------------------------------------------------
// Kernel 1: streaming tanh-softmax context.
// R8: R7's macro-based double-buffer silently failed to unroll -> the
// BATCH=8 x2 buffers (96 floats/thread) were demoted to scratch
// (VGPR=64, WRITE_SIZE=94MB of spill writeback, main 85us). Rewritten:
// BATCH=4 double-buffer (48 buffer VGPRs, ~80 total, fits the 128-VGPR
// budget of (256,4) with margin), loops as plain #pragma unroll in
// lambdas -- static indexing guaranteed. CHUNKS=32 (128 rows/block,
// preamble amortized 2x) and grid 1024 = exactly 4 blocks/CU stay.
// Bulk reads stay nontemporal (R4). No __threadfence (R5).
// ---------------------------------------------------------------------------
__global__ __launch_bounds__(256, 4) void
main_kernel(const float* __restrict__ h,
            const float* __restrict__ q,
            const float* __restrict__ pf1,
            const float* __restrict__ pf2,
            float* __restrict__ ws) {
    const int c    = blockIdx.x;
    const int b    = blockIdx.y;
    const int tid  = threadIdx.x;
    const int wave = tid >> 6;
    const int lane = tid & 63;
    const int ll   = lane & 31;

    // per-lane constants: sum the 8 prep partials (L2-hot)
    f4 vh4 = {0.f, 0.f, 0.f, 0.f};
    f4 vq4 = {0.f, 0.f, 0.f, 0.f};
    #pragma unroll
    for (int k = 0; k < VH_SLICES; ++k) {
        vh4 += ((const f4*)(ws + WS_VHP + k * DD))[lane];
        vq4 += ((const f4*)(ws + WS_VQP + k * DD))[lane];
    }
    const f2 vpl = ((const f2*)(ws + WS_VP))[lane];

    // per-batch q scalar, computed redundantly per wave (cached reads)
    const float4 q4 = ((const float4*)(q + (size_t)b * DD))[lane];
    float qp = q4.x * vq4.x + q4.y * vq4.y + q4.z * vq4.z + q4.w * vq4.w;
    #pragma unroll
    for (int off = 32; off >= 1; off >>= 1) qp += __shfl_xor(qp, off, 64);
    const float qd = qp + ws[WS_BC];

    const int s0 = c * ROWS_PER_BLOCK + wave * ROWS_PER_WAVE;
    const f4*    hbase = (const f4*)(h + (size_t)b * SS * DD);
    const float* pfsel = ((lane < 32) ? pf1 : pf2) + (size_t)b * SS * DPP + 2 * ll;

    float  l = 0.f;
    float4 ctx = make_float4(0.f, 0.f, 0.f, 0.f);

    f4 hA[BATCH], hB[BATCH];
    f2 pA[BATCH], pB[BATCH];

    auto loadb = [&](int ib, f4 (&H)[BATCH], f2 (&P)[BATCH]) {
        const int sb = s0 + ib * BATCH;
        #pragma unroll
        for (int j = 0; j < BATCH; ++j) {
            const int s = sb + j;
            H[j] = __builtin_nontemporal_load(hbase + (size_t)s * (DD / 4) + lane);
            P[j] = __builtin_nontemporal_load((const f2*)(pfsel + (size_t)s * DPP));
        }
    };

    auto compute = [&](f4 (&H)[BATCH], f2 (&P)[BATCH]) {
        float part[BATCH];
        #pragma unroll
        for (int j = 0; j < BATCH; ++j)
            part[j] = H[j].x * vh4.x + H[j].y * vh4.y
                    + H[j].z * vh4.z + H[j].w * vh4.w
                    + P[j].x * vpl.x + P[j].y * vpl.y;
        #pragma unroll
        for (int off = 32; off >= 1; off >>= 1) {
            #pragma unroll
            for (int j = 0; j < BATCH; ++j)
                part[j] += __shfl_xor(part[j], off, 64);
        }
        #pragma unroll
        for (int j = 0; j < BATCH; ++j) {
            const float score = part[j] + qd;
            const float e2 = __expf(2.f * score);
            const float t  = 1.f - 2.f * __builtin_amdgcn_rcpf(e2 + 1.f); // tanh
            const float w  = __expf(t);                                   // [0.37, 2.72]
            l += w;
            ctx.x += w * H[j].x;
            ctx.y += w * H[j].y;
            ctx.z += w * H[j].z;
            ctx.w += w * H[j].w;
        }
    };

    // software pipeline over NBATCH=8: compute batch i while batch i+1's
    // loads are in flight
    loadb(0, hA, pA);
    loadb(1, hB, pB);
    compute(hA, pA);  loadb(2, hA, pA);
    compute(hB, pB);  loadb(3, hB, pB);
    compute(hA, pA);  loadb(4, hA, pA);
    compute(hB, pB);  loadb(5, hB, pB);
    compute(hA, pA);  loadb(6, hA, pA);
    compute(hB, pB);  loadb(7, hB, pB);
    compute(hA, pA);
    compute(hB, pB);

    // combine the block's 4 waves in LDS, then one plain store per thread
    __shared__ float s_l[WAVES_PER_BLOCK];
    __shared__ float s_ctx[WAVES_PER_BLOCK][DD];
    if (lane == 0) s_l[wave] = l;
    ((float4*)s_ctx[wave])[lane] = ctx;
    __syncthreads();

    const float cd = s_ctx[0][tid] + s_ctx[1][tid] + s_ctx[2][tid] + s_ctx[3][tid];
    float* part_out = ws + WS_PART + (size_t)(b * CHUNKS + c) * PART_STRIDE;
    part_out[1 + tid] = cd;
    if (tid == 0) part_out[0] = s_l[0] + s_l[1] + s_l[2] + s_l[3];
}

// ---------------------------------------------------------------------------
// Kernel 2: merge the CHUNKS partials per batch, scale by 1/(L*S).
// ---------------------------------------------------------------------------
__global__ void finalize_kernel(const float* __restrict__ ws,
                                float* __restrict__ out) {
    const int b   = blockIdx.x;
    const int tid = threadIdx.x; // 256
    __shared__ float s_l[CHUNKS];
    const float* base = ws + WS_PART + (size_t)b * CHUNKS * PART_STRIDE;
    if (tid < CHUNKS) s_l[tid] = base[(size_t)tid * PART_STRIDE];
    __syncthreads();
    float L = 0.f, acc = 0.f;
    #pragma unroll 8
    for (int c = 0; c < CHUNKS; ++c) {
        L   += s_l[c];
        acc += base[(size_t)c * PART_STRIDE + 1 + tid];
    }
    out[b * DD + tid] = acc / (L * (float)SS);
}

extern "C" void kernel_launch(void* const* d_in, const int* in_sizes, int n_in,
                              void* d_out, int out_size, void* d_ws, size_t ws_size,
                              hipStream_t stream) {
    const float* h   = (const float*)d_in[0];
    const float* q   = (const float*)d_in[1];
    const float* pf1 = (const float*)d_in[2];
    const float* pf2 = (const float*)d_in[3];
    const float* Wh  = (const float*)d_in[4];
    const float* Wq  = (const float*)d_in[5];
    const float* Wp1 = (const float*)d_in[6];
    const float* Wp2 = (const float*)d_in[7];
    const float* Wc  = (const float*)d_in[8];
    const float* bc  = (const float*)d_in[9];
    float* out = (float*)d_out;
    float* ws  = (float*)d_ws;

    prep_kernel<<<VH_SLICES + 1, 256, 0, stream>>>(Wh, Wq, Wp1, Wp2, Wc, bc, ws);
    main_kernel<<<dim3(CHUNKS, BB), 256, 0, stream>>>(h, q, pf1, pf2, ws);
    finalize_kernel<<<BB, 256, 0, stream>>>(ws, out);
}

// Round 4
// 243.588 us; speedup vs baseline: 1.1738x; 1.1098x over previous
//
#include <hip/hip_runtime.h>
#include <math.h>

#define BB 32
#define SS 4096
#define DD 256
#define DAA 128
#define DPP 64
#define CHUNKS 32
#define ROWS_PER_BLOCK (SS / CHUNKS)                     // 128
#define WAVES_PER_BLOCK 4
#define ROWS_PER_WAVE (ROWS_PER_BLOCK / WAVES_PER_BLOCK) // 32
#define BATCH 8
#define NBATCH (ROWS_PER_WAVE / BATCH)                   // 4
#define VH_SLICES 8
#define SLICE (DAA / VH_SLICES)                          // 16

// workspace layout (float elements)
#define WS_VHP  0                         // 8 x 256 partial vh
#define WS_VQP  (WS_VHP + VH_SLICES*DD)   // 8 x 256 partial vq
#define WS_VP   (WS_VQP + VH_SLICES*DD)   // 128: [vp1[64] | vp2[64]]
#define WS_BC   (WS_VP + 128)
#define WS_PART (WS_BC + 16)              // 16B-aligned
#define PART_STRIDE 258                   // [l, ctx[256], pad]

typedef float f4 __attribute__((ext_vector_type(4)));
typedef float f2 __attribute__((ext_vector_type(2)));

// ---------------------------------------------------------------------------
// Kernel 0: fold Wc into projection vectors. Blocks 0..7 each do a 16-row
// slice of the Wh/Wq dots; block 8 does vp1/vp2/bc. main sums the 8
// partials per lane.
// ---------------------------------------------------------------------------
__global__ void prep_kernel(const float* __restrict__ Wh,
                            const float* __restrict__ Wq,
                            const float* __restrict__ Wp1,
                            const float* __restrict__ Wp2,
                            const float* __restrict__ Wc,
                            const float* __restrict__ bc,
                            float* __restrict__ ws) {
    const int tid = threadIdx.x; // 256 threads
    const int blk = blockIdx.x;
    if (blk < VH_SLICES) {
        const int a0 = blk * SLICE;
        float vh = 0.f, vq = 0.f;
        #pragma unroll
        for (int i = 0; i < SLICE; ++i) {
            const int a = a0 + i;
            vh += Wh[a * DD + tid] * Wc[a];
            vq += Wq[a * DD + tid] * Wc[DAA + a];
        }
        ws[WS_VHP + blk * DD + tid] = vh;
        ws[WS_VQP + blk * DD + tid] = vq;
    } else {
        if (tid < DPP) {
            float vp1 = 0.f, vp2 = 0.f;
            for (int a = 0; a < DPP; ++a) {
                vp1 += Wp1[a * DPP + tid] * Wc[2 * DAA + a];
                vp2 += Wp2[a * DPP + tid] * Wc[2 * DAA + DPP + a];
            }
            ws[WS_VP + tid]       = vp1;   // lanes 0..31 read pairs from here
            ws[WS_VP + DPP + tid] = vp2;   // lanes 32..63 read pairs from here
        }
        if (tid == 0) ws[WS_BC] = bc[0];
    }
}

// ---------------------------------------------------------------------------
// Kernel 1: streaming tanh-softmax context. tanh(score) in [-1,1] so
// exp(t) in [0.37,2.72] -> plain accumulation, no online max.
// R9: EXACT R1/R6 loop structure restored (plain for-ib loop, arrays only
// indexed inside #pragma-unroll inner loops -> PromoteAlloca succeeds;
// R7/R8's macro/lambda forms escaped the arrays to scratch: VGPR=64,
// 77-94MB spill writeback, +25-41us). Only change vs R1: CHUNKS 64->32.
// 128 rows/block halves the preamble count (2048->1024 blocks) and makes
// grid = 1024 = exactly 4 resident blocks/CU at (256,6) -> one balanced
// round. Bulk reads nontemporal (R4). No __threadfence (R5).
// ---------------------------------------------------------------------------
__global__ __launch_bounds__(256, 6) void
main_kernel(const float* __restrict__ h,
            const float* __restrict__ q,
            const float* __restrict__ pf1,
            const float* __restrict__ pf2,
            float* __restrict__ ws) {
    const int c    = blockIdx.x;
    const int b    = blockIdx.y;
    const int tid  = threadIdx.x;
    const int wave = tid >> 6;
    const int lane = tid & 63;
    const int ll   = lane & 31;

    // per-lane constants: sum the 8 prep partials (L2-hot)
    f4 vh4 = {0.f, 0.f, 0.f, 0.f};
    f4 vq4 = {0.f, 0.f, 0.f, 0.f};
    #pragma unroll
    for (int k = 0; k < VH_SLICES; ++k) {
        vh4 += ((const f4*)(ws + WS_VHP + k * DD))[lane];
        vq4 += ((const f4*)(ws + WS_VQP + k * DD))[lane];
    }
    const f2 vpl = ((const f2*)(ws + WS_VP))[lane];

    // per-batch q scalar, computed redundantly per wave (cached reads)
    const float4 q4 = ((const float4*)(q + (size_t)b * DD))[lane];
    float qp = q4.x * vq4.x + q4.y * vq4.y + q4.z * vq4.z + q4.w * vq4.w;
    #pragma unroll
    for (int off = 32; off >= 1; off >>= 1) qp += __shfl_xor(qp, off, 64);
    const float qd = qp + ws[WS_BC];

    const int s0 = c * ROWS_PER_BLOCK + wave * ROWS_PER_WAVE;
    const f4*    hbase = (const f4*)(h + (size_t)b * SS * DD);
    const float* pfsel = ((lane < 32) ? pf1 : pf2) + (size_t)b * SS * DPP + 2 * ll;

    float  l = 0.f;
    float4 ctx = make_float4(0.f, 0.f, 0.f, 0.f);

    for (int ib = 0; ib < NBATCH; ++ib) {
        const int sb = s0 + ib * BATCH;
        f4    h4[BATCH];
        f2    pv[BATCH];
        float part[BATCH];
        #pragma unroll
        for (int j = 0; j < BATCH; ++j) {
            const int s = sb + j;
            h4[j] = __builtin_nontemporal_load(hbase + (size_t)s * (DD / 4) + lane);
            pv[j] = __builtin_nontemporal_load((const f2*)(pfsel + (size_t)s * DPP));
        }
        #pragma unroll
        for (int j = 0; j < BATCH; ++j) {
            part[j] = h4[j].x * vh4.x + h4[j].y * vh4.y
                    + h4[j].z * vh4.z + h4[j].w * vh4.w
                    + pv[j].x * vpl.x + pv[j].y * vpl.y;
        }
        // 8 independent butterfly chains, interleaved by the compiler
        #pragma unroll
        for (int off = 32; off >= 1; off >>= 1) {
            #pragma unroll
            for (int j = 0; j < BATCH; ++j)
                part[j] += __shfl_xor(part[j], off, 64);
        }
        #pragma unroll
        for (int j = 0; j < BATCH; ++j) {
            const float score = part[j] + qd;
            const float e2 = __expf(2.f * score);
            const float t  = 1.f - 2.f * __builtin_amdgcn_rcpf(e2 + 1.f); // tanh
            const float w  = __expf(t);                                   // [0.37, 2.72]
            l += w;
            ctx.x += w * h4[j].x;
            ctx.y += w * h4[j].y;
            ctx.z += w * h4[j].z;
            ctx.w += w * h4[j].w;
        }
    }

    // combine the block's 4 waves in LDS, then one plain store per thread
    __shared__ float s_l[WAVES_PER_BLOCK];
    __shared__ float s_ctx[WAVES_PER_BLOCK][DD];
    if (lane == 0) s_l[wave] = l;
    ((float4*)s_ctx[wave])[lane] = ctx;
    __syncthreads();

    const float cd = s_ctx[0][tid] + s_ctx[1][tid] + s_ctx[2][tid] + s_ctx[3][tid];
    float* part_out = ws + WS_PART + (size_t)(b * CHUNKS + c) * PART_STRIDE;
    part_out[1 + tid] = cd;
    if (tid == 0) part_out[0] = s_l[0] + s_l[1] + s_l[2] + s_l[3];
}

// ---------------------------------------------------------------------------
// Kernel 2: merge the CHUNKS partials per batch, scale by 1/(L*S).
// ---------------------------------------------------------------------------
__global__ void finalize_kernel(const float* __restrict__ ws,
                                float* __restrict__ out) {
    const int b   = blockIdx.x;
    const int tid = threadIdx.x; // 256
    __shared__ float s_l[CHUNKS];
    const float* base = ws + WS_PART + (size_t)b * CHUNKS * PART_STRIDE;
    if (tid < CHUNKS) s_l[tid] = base[(size_t)tid * PART_STRIDE];
    __syncthreads();
    float L = 0.f, acc = 0.f;
    #pragma unroll 8
    for (int c = 0; c < CHUNKS; ++c) {
        L   += s_l[c];
        acc += base[(size_t)c * PART_STRIDE + 1 + tid];
    }
    out[b * DD + tid] = acc / (L * (float)SS);
}

extern "C" void kernel_launch(void* const* d_in, const int* in_sizes, int n_in,
                              void* d_out, int out_size, void* d_ws, size_t ws_size,
                              hipStream_t stream) {
    const float* h   = (const float*)d_in[0];
    const float* q   = (const float*)d_in[1];
    const float* pf1 = (const float*)d_in[2];
    const float* pf2 = (const float*)d_in[3];
    const float* Wh  = (const float*)d_in[4];
    const float* Wq  = (const float*)d_in[5];
    const float* Wp1 = (const float*)d_in[6];
    const float* Wp2 = (const float*)d_in[7];
    const float* Wc  = (const float*)d_in[8];
    const float* bc  = (const float*)d_in[9];
    float* out = (float*)d_out;
    float* ws  = (float*)d_ws;

    prep_kernel<<<VH_SLICES + 1, 256, 0, stream>>>(Wh, Wq, Wp1, Wp2, Wc, bc, ws);
    main_kernel<<<dim3(CHUNKS, BB), 256, 0, stream>>>(h, q, pf1, pf2, ws);
    finalize_kernel<<<BB, 256, 0, stream>>>(ws, out);
}